// Round 1
// baseline (337.689 us; speedup 1.0000x reference)
//
#include <hip/hip_runtime.h>

// Problem constants (from reference):
//   BATCH=64, NFILT=512, TFULL=1024, FFT_N=512 (rfft truncates y to first 512 samples)
//   bcoef = (fc/Q) * 0.5*sqrt(2*pi) / FS ;  om = 2*pi/FS * fc
//   y[b,f,t] = exp(-(bcoef*n)^2) * cos(om*n),  n = t+1  (t = 0..1023)
//   maxfft[f] = max_{b,k} |DFT_512(y[b,f,0:512])[k]|,  k = 0..256
//   out[b,f,t] = y[b,f,1023-t] / maxfft[f]   (i.e. n = 1024 - t)

#define BCOEF_K 7.8332133582218756e-05f  // 0.5*sqrt(2*pi)/16000
#define OMEGA_K 3.9269908169872414e-04f  // 2*pi/16000
#define PI_F    3.14159265358979323846f

// ---------------------------------------------------------------------------
// Kernel 1: per (b,f) block computes 512-sample signal in LDS, then Goertzel
// per bin k=tid (257th bin = Nyquist via alternating sum), block-max, atomic
// max into maxsq[f] (float-as-int, valid for non-negative values).
// ---------------------------------------------------------------------------
__global__ __launch_bounds__(256) void k_maxfft(const float* __restrict__ Q,
                                                const float* __restrict__ fc,
                                                float* __restrict__ maxsq) {
  const int blk = blockIdx.x;      // bb*512 + f
  const int f   = blk & 511;
  const int bb  = blk >> 9;
  const int tid = threadIdx.x;     // 0..255

  __shared__ __align__(16) float y[512];
  __shared__ float red[256];

  const float fcv = fc[f];
  const float q   = Q[bb * 512 + f];
  const float bc  = (fcv / q) * BCOEF_K;
  const float om  = OMEGA_K * fcv;

  // Signal for the FFT: first 512 samples (n = t+1, t = 0..511).
  float alt;
  {
    const int   t0 = tid * 2;
    const float n0 = (float)(t0 + 1);
    const float n1 = (float)(t0 + 2);
    const float x0 = bc * n0;
    const float x1 = bc * n1;
    const float v0 = expf(-x0 * x0) * cosf(om * n0);
    const float v1 = expf(-x1 * x1) * cosf(om * n1);
    y[t0]     = v0;
    y[t0 + 1] = v1;
    alt = v0 - v1;                 // (+1)^even + (-1)^odd partial (Nyquist bin)
  }
  red[tid] = alt;
  __syncthreads();
  #pragma unroll
  for (int s = 128; s > 0; s >>= 1) {
    if (tid < s) red[tid] += red[tid + s];
    __syncthreads();
  }
  const float altsum = red[0];     // X[256] = sum (-1)^t y[t]
  __syncthreads();

  // Goertzel for bin k = tid: s[t] = y[t] + c*s[t-1] - s[t-2], c = 2cos(2*pi*k/512)
  // |X[k]|^2 = s1^2 + s2^2 - c*s1*s2
  const float c = 2.0f * cosf((float)tid * (PI_F / 256.0f));
  float s1 = 0.0f, s2 = 0.0f;
  const float4* y4 = (const float4*)y;
  #pragma unroll 8
  for (int j = 0; j < 128; ++j) {
    const float4 v = y4[j];        // wave-uniform broadcast read (conflict-free)
    float s;
    s = fmaf(c, s1, v.x - s2); s2 = s1; s1 = s;
    s = fmaf(c, s1, v.y - s2); s2 = s1; s1 = s;
    s = fmaf(c, s1, v.z - s2); s2 = s1; s1 = s;
    s = fmaf(c, s1, v.w - s2); s2 = s1; s1 = s;
  }
  float magsq = fmaf(s1, s1, fmaf(s2, s2, -(c * s1 * s2)));
  if (tid == 0) magsq = fmaxf(magsq, altsum * altsum);

  red[tid] = magsq;
  __syncthreads();
  #pragma unroll
  for (int s = 128; s > 0; s >>= 1) {
    if (tid < s) red[tid] = fmaxf(red[tid], red[tid + s]);
    __syncthreads();
  }
  if (tid == 0) {
    // mag^2 >= 0 so int-compare == float-compare; ws zeroed each launch.
    atomicMax((int*)(maxsq + f), __float_as_int(red[0]));
  }
}

// ---------------------------------------------------------------------------
// Kernel 2: one block per (b,f) row; thread tid writes out[t0..t0+3] as float4
// with n = 1024 - t (time flip), scaled by 1/sqrt(maxsq[f]).
// ---------------------------------------------------------------------------
__global__ __launch_bounds__(256) void k_write(const float* __restrict__ Q,
                                               const float* __restrict__ fc,
                                               const float* __restrict__ maxsq,
                                               float* __restrict__ out) {
  const int blk = blockIdx.x;      // bb*512 + f
  const int f   = blk & 511;
  const int bb  = blk >> 9;
  const int tid = threadIdx.x;

  const float fcv = fc[f];
  const float q   = Q[bb * 512 + f];
  const float bc  = (fcv / q) * BCOEF_K;
  const float om  = OMEGA_K * fcv;
  const float inv = 1.0f / sqrtf(maxsq[f]);

  const int t0 = tid * 4;
  float4 r;
  {
    const float n0 = (float)(1024 - t0);
    const float n1 = (float)(1023 - t0);
    const float n2 = (float)(1022 - t0);
    const float n3 = (float)(1021 - t0);
    const float x0 = bc * n0, x1 = bc * n1, x2 = bc * n2, x3 = bc * n3;
    r.x = expf(-x0 * x0) * cosf(om * n0) * inv;
    r.y = expf(-x1 * x1) * cosf(om * n1) * inv;
    r.z = expf(-x2 * x2) * cosf(om * n2) * inv;
    r.w = expf(-x3 * x3) * cosf(om * n3) * inv;
  }
  ((float4*)out)[blk * 256 + tid] = r;
}

// ---------------------------------------------------------------------------
extern "C" void kernel_launch(void* const* d_in, const int* in_sizes, int n_in,
                              void* d_out, int out_size, void* d_ws, size_t ws_size,
                              hipStream_t stream) {
  const float* Q  = (const float*)d_in[0];   // [64, 512] f32
  const float* fc = (const float*)d_in[1];   // [512] f32
  float* out      = (float*)d_out;           // [64, 512, 1024] f32
  float* maxsq    = (float*)d_ws;            // [512] f32 scratch (max |FFT|^2)

  // ws is re-poisoned to 0xAA before every launch; zero the atomic-max targets.
  hipMemsetAsync(maxsq, 0, 512 * sizeof(float), stream);

  const int nblk = 64 * 512;
  k_maxfft<<<nblk, 256, 0, stream>>>(Q, fc, maxsq);
  k_write <<<nblk, 256, 0, stream>>>(Q, fc, maxsq, out);
}

// Round 2
// 308.940 us; speedup vs baseline: 1.0931x; 1.0931x over previous
//
#include <hip/hip_runtime.h>

// Problem: BATCH=64, NFILT=512, T=1024, FFT over first 512 samples, 257 bins.
//   bc = (fc/Q)*0.5*sqrt(2pi)/FS ; om = 2pi/FS*fc ; n = t+1
//   y[b,f,t] = exp(-(bc*n)^2) * cos(om*n)
//   maxsq[f] = max_{b,k} |DFT_512(y[b,f,0:512])[k]|^2
//   out[b,f,t] = y[b,f,1023-t] / sqrt(maxsq[f])
//
// R2: wave-per-signal Goertzel (4 bins/lane, shfl reductions) -> 4x fewer LDS
// issues; HW v_exp/v_cos via __expf/__cosf on revolution-reduced phase.

#define BCOEF_K 7.8332133582218756e-05f  // 0.5*sqrt(2*pi)/16000
#define INV_FS  6.25e-05f                // 1/16000
#define TWO_PI  6.28318530717958647692f
#define PI_F    3.14159265358979323846f

// cos(2*pi * n * fcn) with fcn = fc/FS, phase reduced in revolutions.
__device__ __forceinline__ float fast_carrier(float fcn, float n) {
  float rev = fcn * n;
  float fr  = rev - floorf(rev);       // [0,1)
  return __cosf(TWO_PI * fr);          // native v_cos path
}

// exp(-(x)^2) via native v_exp
__device__ __forceinline__ float fast_env(float x) {
  return __expf(-x * x);
}

// ---------------------------------------------------------------------------
// Kernel 1: block = 256 threads = 4 waves; wave w owns signal sig = blk*4+w.
// Wave generates its 512-sample signal into its own LDS row (2 float4 stores
// per lane), then each lane Goertzels 4 bins (k = lane + 64j) reading the row
// as wave-uniform float4 broadcasts. Nyquist bin via alternating shfl-sum.
// ---------------------------------------------------------------------------
__global__ __launch_bounds__(256) void k_maxfft(const float* __restrict__ Q,
                                                const float* __restrict__ fc,
                                                float* __restrict__ maxsq) {
  const int tid  = threadIdx.x;
  const int w    = tid >> 6;          // wave 0..3
  const int lane = tid & 63;
  const int sig  = blockIdx.x * 4 + w; // bb*512 + f
  const int f    = sig & 511;
  const int bb   = sig >> 9;

  __shared__ __align__(16) float ybuf[4][512];

  const float fcv = fc[f];
  const float q   = Q[bb * 512 + f];
  const float bc  = (fcv / q) * BCOEF_K;
  const float fcn = fcv * INV_FS;

  // --- generate 8 samples per lane: t = 8*lane + m, n = t+1 ---
  float v[8];
  float alt = 0.0f;                    // sum (-1)^t y[t] (t parity == m parity)
  #pragma unroll
  for (int m = 0; m < 8; ++m) {
    const float n = (float)(8 * lane + m + 1);
    const float s = fast_env(bc * n) * fast_carrier(fcn, n);
    v[m] = s;
    alt += (m & 1) ? -s : s;
  }
  float* yw = &ybuf[w][0];
  ((float4*)(yw + 8 * lane))[0] = make_float4(v[0], v[1], v[2], v[3]);
  ((float4*)(yw + 8 * lane))[1] = make_float4(v[4], v[5], v[6], v[7]);
  __syncthreads();

  // --- Goertzel coefficients for bins k = lane + 64j (accurate libm cos) ---
  float c0 = 2.0f * cosf((float)(lane      ) * (PI_F / 256.0f));
  float c1 = 2.0f * cosf((float)(lane + 64 ) * (PI_F / 256.0f));
  float c2 = 2.0f * cosf((float)(lane + 128) * (PI_F / 256.0f));
  float c3 = 2.0f * cosf((float)(lane + 192) * (PI_F / 256.0f));

  float s1a = 0.f, s2a = 0.f, s1b = 0.f, s2b = 0.f;
  float s1c = 0.f, s2c = 0.f, s1d = 0.f, s2d = 0.f;

  const float4* y4 = (const float4*)yw;   // wave-uniform broadcast reads
  #pragma unroll 4
  for (int j = 0; j < 128; ++j) {
    const float4 x = y4[j];
    float s;
    #define STEP(val) \
      s = fmaf(c0, s1a, (val) - s2a); s2a = s1a; s1a = s; \
      s = fmaf(c1, s1b, (val) - s2b); s2b = s1b; s1b = s; \
      s = fmaf(c2, s1c, (val) - s2c); s2c = s1c; s1c = s; \
      s = fmaf(c3, s1d, (val) - s2d); s2d = s1d; s1d = s;
    STEP(x.x) STEP(x.y) STEP(x.z) STEP(x.w)
    #undef STEP
  }

  float m0 = fmaf(s1a, s1a, fmaf(s2a, s2a, -(c0 * s1a * s2a)));
  float m1 = fmaf(s1b, s1b, fmaf(s2b, s2b, -(c1 * s1b * s2b)));
  float m2 = fmaf(s1c, s1c, fmaf(s2c, s2c, -(c2 * s1c * s2c)));
  float m3 = fmaf(s1d, s1d, fmaf(s2d, s2d, -(c3 * s1d * s2d)));
  float mx = fmaxf(fmaxf(m0, m1), fmaxf(m2, m3));

  // --- wave reductions: max(mx), sum(alt) ---
  #pragma unroll
  for (int d = 32; d > 0; d >>= 1) {
    mx  = fmaxf(mx, __shfl_xor(mx, d));
    alt += __shfl_xor(alt, d);
  }
  if (lane == 0) {
    mx = fmaxf(mx, alt * alt);        // Nyquist bin k=256
    atomicMax((int*)(maxsq + f), __float_as_int(mx));  // all values >= 0
  }
}

// ---------------------------------------------------------------------------
// Kernel 2: one block per (b,f) row; thread tid writes float4 at t0 = 4*tid,
// n = 1024 - t (flip), scaled by 1/sqrt(maxsq[f]). Fast trig -> write-bound.
// ---------------------------------------------------------------------------
__global__ __launch_bounds__(256) void k_write(const float* __restrict__ Q,
                                               const float* __restrict__ fc,
                                               const float* __restrict__ maxsq,
                                               float* __restrict__ out) {
  const int blk = blockIdx.x;      // bb*512 + f
  const int f   = blk & 511;
  const int bb  = blk >> 9;
  const int tid = threadIdx.x;

  const float fcv = fc[f];
  const float q   = Q[bb * 512 + f];
  const float bc  = (fcv / q) * BCOEF_K;
  const float fcn = fcv * INV_FS;
  const float inv = 1.0f / sqrtf(maxsq[f]);

  const int t0 = tid * 4;
  float4 r;
  {
    const float n0 = (float)(1024 - t0);
    const float n1 = (float)(1023 - t0);
    const float n2 = (float)(1022 - t0);
    const float n3 = (float)(1021 - t0);
    r.x = fast_env(bc * n0) * fast_carrier(fcn, n0) * inv;
    r.y = fast_env(bc * n1) * fast_carrier(fcn, n1) * inv;
    r.z = fast_env(bc * n2) * fast_carrier(fcn, n2) * inv;
    r.w = fast_env(bc * n3) * fast_carrier(fcn, n3) * inv;
  }
  ((float4*)out)[blk * 256 + tid] = r;
}

// ---------------------------------------------------------------------------
extern "C" void kernel_launch(void* const* d_in, const int* in_sizes, int n_in,
                              void* d_out, int out_size, void* d_ws, size_t ws_size,
                              hipStream_t stream) {
  const float* Q  = (const float*)d_in[0];   // [64, 512] f32
  const float* fc = (const float*)d_in[1];   // [512] f32
  float* out      = (float*)d_out;           // [64, 512, 1024] f32
  float* maxsq    = (float*)d_ws;            // [512] f32 scratch (max |FFT|^2)

  hipMemsetAsync(maxsq, 0, 512 * sizeof(float), stream);

  k_maxfft<<<64 * 512 / 4, 256, 0, stream>>>(Q, fc, maxsq);
  k_write <<<64 * 512,     256, 0, stream>>>(Q, fc, maxsq, out);
}

// Round 4
// 199.833 us; speedup vs baseline: 1.6899x; 1.5460x over previous
//
#include <hip/hip_runtime.h>

// Problem: BATCH=64, NFILT=512, T=1024, FFT over first 512 samples, 257 bins.
//   bc = (fc/Q)*0.5*sqrt(2pi)/FS ; n = t+1
//   y[b,f,t] = exp(-(bc*n)^2) * cos(2pi*fc/FS*n)
//   maxsq[f] = max_{b,k} |DFT_512(y[b,f,0:512])[k]|^2
//   out[b,f,t] = y[b,f,1023-t] * rsqrt(maxsq[f])
//
// R4 = R3 with the nontemporal-store type fixed (Clang ext_vector, not
// HIP_vector_type):
// (1) bin windowing — |X[k]| is a unimodal Gaussian bump (sigma_k =
// 115.2*bc bins) centered at k_c = fc*512/FS; argmax bin is always within
// k_c +/- (2*sigma_k+6). Goertzel only that window (1 chain/lane/iter,
// avg ~1.2 iter vs fixed 4 chains) -> ~3.3x fewer VALU ops.
// (2) k_write: nontemporal float4 stores (bypass L2 write-allocate).

#define BCOEF_K 7.8332133582218756e-05f  // 0.5*sqrt(2*pi)/16000
#define INV_FS  6.25e-05f                // 1/16000
#define TWO_PI  6.28318530717958647692f
#define PI_F    3.14159265358979323846f
#define SIGK_K  115.2309f                // sqrt(2)*512/(2*pi)

typedef float vf4 __attribute__((ext_vector_type(4)));  // nt-store compatible

// cos(2*pi * n * fcn), phase reduced in revolutions -> native v_cos.
__device__ __forceinline__ float fast_carrier(float fcn, float n) {
  float rev = fcn * n;
  float fr  = rev - floorf(rev);
  return __cosf(TWO_PI * fr);
}

__device__ __forceinline__ float fast_env(float x) { return __expf(-x * x); }

// ---------------------------------------------------------------------------
// Kernel 1: block = 4 waves; wave w owns signal sig = blk*4+w. Wave generates
// its 512 samples into its LDS row, then Goertzels only the bins in the
// window [k_lo, k_hi] around the spectral peak, 1 bin/lane/iteration.
// Bins 0 and 256 are plain Goertzel cases (c=+2/-2), no special-casing.
// ---------------------------------------------------------------------------
__global__ __launch_bounds__(256) void k_maxfft(const float* __restrict__ Q,
                                                const float* __restrict__ fc,
                                                float* __restrict__ maxsq) {
  const int tid  = threadIdx.x;
  const int w    = tid >> 6;           // wave 0..3
  const int lane = tid & 63;
  const int sig  = blockIdx.x * 4 + w; // bb*512 + f
  const int f    = sig & 511;
  const int bb   = sig >> 9;

  __shared__ __align__(16) float ybuf[4][512];

  const float fcv = fc[f];
  const float q   = Q[bb * 512 + f];
  const float bc  = (fcv / q) * BCOEF_K;
  const float fcn = fcv * INV_FS;

  // --- generate 8 samples per lane: t = 8*lane + m, n = t+1 ---
  float v[8];
  #pragma unroll
  for (int m = 0; m < 8; ++m) {
    const float n = (float)(8 * lane + m + 1);
    v[m] = fast_env(bc * n) * fast_carrier(fcn, n);
  }
  float* yw = &ybuf[w][0];
  ((float4*)(yw + 8 * lane))[0] = make_float4(v[0], v[1], v[2], v[3]);
  ((float4*)(yw + 8 * lane))[1] = make_float4(v[4], v[5], v[6], v[7]);
  __syncthreads();

  // --- spectral-peak window (wave-uniform) ---
  const float kc   = fcn * 512.0f;              // center bin (continuous)
  const int   kci  = (int)(kc + 0.5f);
  const int   W    = (int)(2.0f * (bc * SIGK_K)) + 6;
  const int   k_lo = max(0, kci - W);
  const int   k_hi = min(256, kci + W);
  const int   nit  = ((k_hi - k_lo) >> 6) + 1;  // 1..5 iterations

  const float4* y4 = (const float4*)yw;         // wave-uniform broadcasts
  float mx = 0.0f;

  for (int it = 0; it < nit; ++it) {            // wave-uniform trip count
    const int   k = min(k_lo + (it << 6) + lane, k_hi);  // dup bins harmless
    const float c = 2.0f * cosf((float)k * (PI_F / 256.0f));
    float s1 = 0.0f, s2 = 0.0f;
    #pragma unroll 8
    for (int j = 0; j < 128; ++j) {
      const float4 x = y4[j];
      float s;
      s = fmaf(c, s1, x.x - s2); s2 = s1; s1 = s;
      s = fmaf(c, s1, x.y - s2); s2 = s1; s1 = s;
      s = fmaf(c, s1, x.z - s2); s2 = s1; s1 = s;
      s = fmaf(c, s1, x.w - s2); s2 = s1; s1 = s;
    }
    mx = fmaxf(mx, fmaf(s1, s1, fmaf(s2, s2, -(c * s1 * s2))));
  }

  #pragma unroll
  for (int d = 32; d > 0; d >>= 1) mx = fmaxf(mx, __shfl_xor(mx, d));
  if (lane == 0) {
    atomicMax((int*)(maxsq + f), __float_as_int(mx));  // all values >= 0
  }
}

// ---------------------------------------------------------------------------
// Kernel 2: one block per (b,f) row; thread tid writes float4 at t0 = 4*tid,
// n = 1024 - t (flip), scaled by rsqrt(maxsq[f]). Nontemporal streaming store.
// ---------------------------------------------------------------------------
__global__ __launch_bounds__(256) void k_write(const float* __restrict__ Q,
                                               const float* __restrict__ fc,
                                               const float* __restrict__ maxsq,
                                               float* __restrict__ out) {
  const int blk = blockIdx.x;      // bb*512 + f
  const int f   = blk & 511;
  const int bb  = blk >> 9;
  const int tid = threadIdx.x;

  const float fcv = fc[f];
  const float q   = Q[bb * 512 + f];
  const float bc  = (fcv / q) * BCOEF_K;
  const float fcn = fcv * INV_FS;
  const float inv = rsqrtf(maxsq[f]);

  const int t0 = tid * 4;
  vf4 r;
  {
    const float n0 = (float)(1024 - t0);
    const float n1 = (float)(1023 - t0);
    const float n2 = (float)(1022 - t0);
    const float n3 = (float)(1021 - t0);
    r.x = fast_env(bc * n0) * fast_carrier(fcn, n0) * inv;
    r.y = fast_env(bc * n1) * fast_carrier(fcn, n1) * inv;
    r.z = fast_env(bc * n2) * fast_carrier(fcn, n2) * inv;
    r.w = fast_env(bc * n3) * fast_carrier(fcn, n3) * inv;
  }
  __builtin_nontemporal_store(r, &((vf4*)out)[blk * 256 + tid]);
}

// ---------------------------------------------------------------------------
extern "C" void kernel_launch(void* const* d_in, const int* in_sizes, int n_in,
                              void* d_out, int out_size, void* d_ws, size_t ws_size,
                              hipStream_t stream) {
  const float* Q  = (const float*)d_in[0];   // [64, 512] f32
  const float* fc = (const float*)d_in[1];   // [512] f32
  float* out      = (float*)d_out;           // [64, 512, 1024] f32
  float* maxsq    = (float*)d_ws;            // [512] f32 scratch (max |FFT|^2)

  (void)hipMemsetAsync(maxsq, 0, 512 * sizeof(float), stream);

  k_maxfft<<<64 * 512 / 4, 256, 0, stream>>>(Q, fc, maxsq);
  k_write <<<64 * 512,     256, 0, stream>>>(Q, fc, maxsq, out);
}

// Round 5
// 172.612 us; speedup vs baseline: 1.9563x; 1.1577x over previous
//
#include <hip/hip_runtime.h>

// Problem: BATCH=64, NFILT=512, T=1024, FFT over first 512 samples, 257 bins.
//   bc = (fc/Q)*0.5*sqrt(2pi)/FS ; n = t+1
//   y[b,f,t] = exp(-(bc*n)^2) * cos(2pi*fc/FS*n)
//   maxsq[f] = max_{b,k} |DFT_512(y[b,f,0:512])[k]|^2
//   out[b,f,t] = y[b,f,1023-t] * rsqrt(maxsq[f])
//
// R5 = R4 + envelope truncation:
//   env(n) = exp(-(bc*n)^2) < e^-16 ~ 1.1e-7 for n > nstar = 4/bc.
//   - k_maxfft: Goertzel/generation only over N_eff = min(512, nstar+2)
//     samples (wave-uniform trip count; median ~62, mean ~135 -> ~3.8x cut).
//     Truncation error on |X| <= 512*1.1e-7 = 6e-5 abs (peak |X| >= 1.4).
//   - k_write: threads whose whole 4-sample quad has n > nstar store zeros
//     (normalized magnitude < 1e-7 << 2.8e-3 threshold) -> store-bound.

#define BCOEF_K 7.8332133582218756e-05f  // 0.5*sqrt(2*pi)/16000
#define INV_FS  6.25e-05f                // 1/16000
#define TWO_PI  6.28318530717958647692f
#define PI_F    3.14159265358979323846f
#define SIGK_K  115.2309f                // sqrt(2)*512/(2*pi)

typedef float vf4 __attribute__((ext_vector_type(4)));  // nt-store compatible

// cos(2*pi * n * fcn), phase reduced in revolutions -> native v_cos.
__device__ __forceinline__ float fast_carrier(float fcn, float n) {
  float rev = fcn * n;
  float fr  = rev - floorf(rev);
  return __cosf(TWO_PI * fr);
}

__device__ __forceinline__ float fast_env(float x) { return __expf(-x * x); }

// ---------------------------------------------------------------------------
// Kernel 1: block = 4 waves; wave w owns signal sig = blk*4+w. Wave generates
// its (truncated) signal into its LDS row, then Goertzels only bins in the
// window [k_lo, k_hi] around the spectral peak, 1 bin/lane/iteration.
// ---------------------------------------------------------------------------
__global__ __launch_bounds__(256) void k_maxfft(const float* __restrict__ Q,
                                                const float* __restrict__ fc,
                                                float* __restrict__ maxsq) {
  const int tid  = threadIdx.x;
  const int w    = tid >> 6;           // wave 0..3
  const int lane = tid & 63;
  const int sig  = blockIdx.x * 4 + w; // bb*512 + f
  const int f    = sig & 511;
  const int bb   = sig >> 9;

  __shared__ __align__(16) float ybuf[4][512];

  const float fcv = fc[f];
  const float q   = Q[bb * 512 + f];
  const float bc  = (fcv / q) * BCOEF_K;
  const float fcn = fcv * INV_FS;

  // --- effective length: env < e^-16 beyond nstar = 4/bc (wave-uniform) ---
  const float nstar = 4.0f / bc;
  const int   N_eff = (nstar >= 510.0f) ? 512 : ((int)nstar + 2);
  const int   jmax  = (N_eff + 3) >> 2;          // float4 groups to process

  // --- generate 8 samples per lane: t = 8*lane + m, n = t+1 (only the
  //     region the Goertzel loop will read) ---
  if (8 * lane < 4 * jmax) {
    float v[8];
    #pragma unroll
    for (int m = 0; m < 8; ++m) {
      const float n = (float)(8 * lane + m + 1);
      v[m] = fast_env(bc * n) * fast_carrier(fcn, n);
    }
    float* yw = &ybuf[w][0];
    ((float4*)(yw + 8 * lane))[0] = make_float4(v[0], v[1], v[2], v[3]);
    ((float4*)(yw + 8 * lane))[1] = make_float4(v[4], v[5], v[6], v[7]);
  }
  __syncthreads();

  // --- spectral-peak window (wave-uniform) ---
  const float kc   = fcn * 512.0f;              // center bin (continuous)
  const int   kci  = (int)(kc + 0.5f);
  const int   W    = (int)(2.0f * (bc * SIGK_K)) + 6;
  const int   k_lo = max(0, kci - W);
  const int   k_hi = min(256, kci + W);
  const int   nit  = ((k_hi - k_lo) >> 6) + 1;  // 1..5 iterations

  const float4* y4 = (const float4*)&ybuf[w][0]; // wave-uniform broadcasts
  float mx = 0.0f;

  for (int it = 0; it < nit; ++it) {            // wave-uniform trip count
    const int   k = min(k_lo + (it << 6) + lane, k_hi);  // dup bins harmless
    const float c = 2.0f * cosf((float)k * (PI_F / 256.0f));
    float s1 = 0.0f, s2 = 0.0f;
    #pragma unroll 4
    for (int j = 0; j < jmax; ++j) {            // wave-uniform trip count
      const float4 x = y4[j];
      float s;
      s = fmaf(c, s1, x.x - s2); s2 = s1; s1 = s;
      s = fmaf(c, s1, x.y - s2); s2 = s1; s1 = s;
      s = fmaf(c, s1, x.z - s2); s2 = s1; s1 = s;
      s = fmaf(c, s1, x.w - s2); s2 = s1; s1 = s;
    }
    mx = fmaxf(mx, fmaf(s1, s1, fmaf(s2, s2, -(c * s1 * s2))));
  }

  #pragma unroll
  for (int d = 32; d > 0; d >>= 1) mx = fmaxf(mx, __shfl_xor(mx, d));
  if (lane == 0) {
    atomicMax((int*)(maxsq + f), __float_as_int(mx));  // all values >= 0
  }
}

// ---------------------------------------------------------------------------
// Kernel 2: one block per (b,f) row; thread tid writes float4 at t0 = 4*tid,
// n = 1024 - t (flip), scaled by rsqrt(maxsq[f]). Threads entirely in the
// dead tail (min n of quad > nstar) store zeros. Nontemporal streaming store.
// ---------------------------------------------------------------------------
__global__ __launch_bounds__(256) void k_write(const float* __restrict__ Q,
                                               const float* __restrict__ fc,
                                               const float* __restrict__ maxsq,
                                               float* __restrict__ out) {
  const int blk = blockIdx.x;      // bb*512 + f
  const int f   = blk & 511;
  const int bb  = blk >> 9;
  const int tid = threadIdx.x;

  const float fcv = fc[f];
  const float q   = Q[bb * 512 + f];
  const float bc  = (fcv / q) * BCOEF_K;
  const float fcn = fcv * INV_FS;
  const float nstar = 4.0f / bc;

  const int t0 = tid * 4;
  vf4 r = {0.0f, 0.0f, 0.0f, 0.0f};
  // quad covers n = 1021-t0 .. 1024-t0; all dead iff smallest n > nstar
  if ((float)(1021 - t0) <= nstar) {
    const float inv = rsqrtf(maxsq[f]);
    const float n0 = (float)(1024 - t0);
    const float n1 = (float)(1023 - t0);
    const float n2 = (float)(1022 - t0);
    const float n3 = (float)(1021 - t0);
    r.x = fast_env(bc * n0) * fast_carrier(fcn, n0) * inv;
    r.y = fast_env(bc * n1) * fast_carrier(fcn, n1) * inv;
    r.z = fast_env(bc * n2) * fast_carrier(fcn, n2) * inv;
    r.w = fast_env(bc * n3) * fast_carrier(fcn, n3) * inv;
  }
  __builtin_nontemporal_store(r, &((vf4*)out)[blk * 256 + tid]);
}

// ---------------------------------------------------------------------------
extern "C" void kernel_launch(void* const* d_in, const int* in_sizes, int n_in,
                              void* d_out, int out_size, void* d_ws, size_t ws_size,
                              hipStream_t stream) {
  const float* Q  = (const float*)d_in[0];   // [64, 512] f32
  const float* fc = (const float*)d_in[1];   // [512] f32
  float* out      = (float*)d_out;           // [64, 512, 1024] f32
  float* maxsq    = (float*)d_ws;            // [512] f32 scratch (max |FFT|^2)

  (void)hipMemsetAsync(maxsq, 0, 512 * sizeof(float), stream);

  k_maxfft<<<64 * 512 / 4, 256, 0, stream>>>(Q, fc, maxsq);
  k_write <<<64 * 512,     256, 0, stream>>>(Q, fc, maxsq, out);
}

// Round 6
// 164.743 us; speedup vs baseline: 2.0498x; 1.0478x over previous
//
#include <hip/hip_runtime.h>

// Problem: BATCH=64, NFILT=512, T=1024, FFT over first 512 samples, 257 bins.
//   bc = (fc/Q)*0.5*sqrt(2pi)/FS ; n = t+1
//   y[b,f,t] = exp(-(bc*n)^2) * cos(2pi*fc/FS*n)
//   maxsq[f] = max_{b,k} |DFT_512(y[b,f,0:512])[k]|^2
//   out[b,f,t] = y[b,f,1023-t] * rsqrt(maxsq[f])
//
// R6: (1) flat 64-bin window centered at kci (all lanes run one Goertzel
// chain anyway -> any window <=64 bins is the same cost; argmax bin is
// provably within +-2 of kc, +-31 is bulletproof). (2) lane-strided signal
// generation scaled to truncated length N_eff (issue cost now scales with
// truncation). (3) no __syncthreads (each wave owns its LDS row), no
// atomics/memset: per-signal results in ws[f*64+b], k_write reduces.

#define BCOEF_K 7.8332133582218756e-05f  // 0.5*sqrt(2*pi)/16000
#define INV_FS  6.25e-05f                // 1/16000
#define TWO_PI  6.28318530717958647692f
#define PI_F    3.14159265358979323846f

typedef float vf4 __attribute__((ext_vector_type(4)));  // nt-store compatible

// cos(2*pi * n * fcn), phase reduced in revolutions -> native v_cos.
__device__ __forceinline__ float fast_carrier(float fcn, float n) {
  float rev = fcn * n;
  float fr  = rev - floorf(rev);
  return __cosf(TWO_PI * fr);
}

__device__ __forceinline__ float fast_env(float x) { return __expf(-x * x); }

// ---------------------------------------------------------------------------
// Kernel 1: block = 4 independent waves; wave w owns signal sig = blk*4+w.
// Wave generates its truncated signal into its private LDS row (lane-strided,
// trip count scales with N_eff), then one Goertzel pass over 64 bins centered
// at the spectral peak. Result -> ws[f*64 + bb]. No barriers, no atomics.
// ---------------------------------------------------------------------------
__global__ __launch_bounds__(256) void k_maxfft(const float* __restrict__ Q,
                                                const float* __restrict__ fc,
                                                float* __restrict__ ws) {
  const int tid  = threadIdx.x;
  const int w    = tid >> 6;           // wave 0..3
  const int lane = tid & 63;
  const int sig  = blockIdx.x * 4 + w; // bb*512 + f
  const int f    = sig & 511;
  const int bb   = sig >> 9;

  __shared__ __align__(16) float ybuf[4][512];

  const float fcv = fc[f];
  const float q   = Q[bb * 512 + f];
  const float bc  = (fcv / q) * BCOEF_K;
  const float fcn = fcv * INV_FS;

  // --- effective length: env < e^-16 beyond nstar = 4/bc (wave-uniform) ---
  const float nstar = 4.0f / bc;
  const int   N_eff = (nstar >= 510.0f) ? 512 : ((int)nstar + 2);
  const int   jmax  = (N_eff + 3) >> 2;      // float4 groups Goertzel reads
  const int   n4    = jmax << 2;             // samples to generate

  // --- lane-strided generation: lane writes samples lane, lane+64, ... ---
  float* yw = &ybuf[w][0];
  const int nit_g = (n4 + 63) >> 6;          // 1..8, wave-uniform
  for (int r = 0; r < nit_g; ++r) {
    const int idx = (r << 6) + lane;         // t index; n = idx+1
    const float n = (float)(idx + 1);
    const float v = fast_env(bc * n) * fast_carrier(fcn, n);
    if (idx < n4) yw[idx] = v;               // masked tail store
  }
  // Wave-local write->read ordering (row is private to this wave).
  asm volatile("s_waitcnt lgkmcnt(0)" ::: "memory");

  // --- one Goertzel pass: 64 bins clamped to [0,256], centered at kci ---
  const int kci = (int)(fcn * 512.0f + 0.5f);
  const int k   = min(max(kci - 31 + lane, 0), 256);
  const float c = 2.0f * cosf((float)k * (PI_F / 256.0f));

  float s1 = 0.0f, s2 = 0.0f;
  const float4* y4 = (const float4*)yw;      // wave-uniform broadcasts
  #pragma unroll 4
  for (int j = 0; j < jmax; ++j) {           // wave-uniform trip count
    const float4 x = y4[j];
    float s;
    s = fmaf(c, s1, x.x - s2); s2 = s1; s1 = s;
    s = fmaf(c, s1, x.y - s2); s2 = s1; s1 = s;
    s = fmaf(c, s1, x.z - s2); s2 = s1; s1 = s;
    s = fmaf(c, s1, x.w - s2); s2 = s1; s1 = s;
  }
  float mx = fmaf(s1, s1, fmaf(s2, s2, -(c * s1 * s2)));

  #pragma unroll
  for (int d = 32; d > 0; d >>= 1) mx = fmaxf(mx, __shfl_xor(mx, d));
  if (lane == 0) ws[f * 64 + bb] = mx;       // per-signal result, no atomic
}

// ---------------------------------------------------------------------------
// Kernel 2: one block per (b,f) row. Each wave loads the 64 per-batch
// results for f, shfl-max -> maxsq[f]; thread tid writes float4 at t0=4*tid,
// n = 1024 - t (flip), scaled by rsqrt(maxsq). Dead tail stores zeros.
// ---------------------------------------------------------------------------
__global__ __launch_bounds__(256) void k_write(const float* __restrict__ Q,
                                               const float* __restrict__ fc,
                                               const float* __restrict__ ws,
                                               float* __restrict__ out) {
  const int blk = blockIdx.x;      // bb*512 + f
  const int f   = blk & 511;
  const int bb  = blk >> 9;
  const int tid = threadIdx.x;

  // max over batch of |X|^2 for this f (64 contiguous floats, L2-hot)
  float mx = ws[f * 64 + (tid & 63)];
  #pragma unroll
  for (int d = 32; d > 0; d >>= 1) mx = fmaxf(mx, __shfl_xor(mx, d));

  const float fcv = fc[f];
  const float q   = Q[bb * 512 + f];
  const float bc  = (fcv / q) * BCOEF_K;
  const float fcn = fcv * INV_FS;
  const float nstar = 4.0f / bc;

  const int t0 = tid * 4;
  vf4 r = {0.0f, 0.0f, 0.0f, 0.0f};
  // quad covers n = 1021-t0 .. 1024-t0; all dead iff smallest n > nstar
  if ((float)(1021 - t0) <= nstar) {
    const float inv = rsqrtf(mx);
    const float n0 = (float)(1024 - t0);
    const float n1 = (float)(1023 - t0);
    const float n2 = (float)(1022 - t0);
    const float n3 = (float)(1021 - t0);
    r.x = fast_env(bc * n0) * fast_carrier(fcn, n0) * inv;
    r.y = fast_env(bc * n1) * fast_carrier(fcn, n1) * inv;
    r.z = fast_env(bc * n2) * fast_carrier(fcn, n2) * inv;
    r.w = fast_env(bc * n3) * fast_carrier(fcn, n3) * inv;
  }
  __builtin_nontemporal_store(r, &((vf4*)out)[blk * 256 + tid]);
}

// ---------------------------------------------------------------------------
extern "C" void kernel_launch(void* const* d_in, const int* in_sizes, int n_in,
                              void* d_out, int out_size, void* d_ws, size_t ws_size,
                              hipStream_t stream) {
  const float* Q  = (const float*)d_in[0];   // [64, 512] f32
  const float* fc = (const float*)d_in[1];   // [512] f32
  float* out      = (float*)d_out;           // [64, 512, 1024] f32
  float* ws       = (float*)d_ws;            // [512*64] per-signal |X|^2 max

  k_maxfft<<<64 * 512 / 4, 256, 0, stream>>>(Q, fc, ws);
  k_write <<<64 * 512,     256, 0, stream>>>(Q, fc, ws, out);
}